// Round 13
// baseline (259.984 us; speedup 1.0000x reference)
//
#include <hip/hip_runtime.h>
#include <math.h>

#define T_TOTAL   131072
#define POSE_FLTS (131072 * 216)       // 28311552
#define BT        64                   // timesteps per scan unit / block
#define NU        (T_TOTAL / BT)       // 2048 units
#define F4PB      (BT * 54)            // 3456 float4 per unit slice
#define FLOOR_YC  (-0.93f)
#define GRAV_Y    (-0.0018f)
#define NEG_INF   (-INFINITY)
#define MAGA      0x5CAB1E01           // aggregate ready
#define MAGP      0x5CAB1E02           // inclusive prefix ready

typedef float floatx4 __attribute__((ext_vector_type(4)));

// ---------------- small math helpers (constant-indexed after inlining) ------

__device__ __forceinline__ void mat3mul(const float* A, const float* B, float* C) {
#pragma unroll
    for (int r = 0; r < 3; ++r) {
#pragma unroll
        for (int c = 0; c < 3; ++c) {
            C[r * 3 + c] = fmaf(A[r * 3 + 2], B[6 + c],
                           fmaf(A[r * 3 + 1], B[3 + c],
                                A[r * 3 + 0] * B[c]));
        }
    }
}

__device__ __forceinline__ void mva(const float* R, const float* b,
                                    const float* pin, float* pout) {
#pragma unroll
    for (int r = 0; r < 3; ++r) {
        pout[r] = pin[r] + fmaf(R[r * 3 + 2], b[2],
                            fmaf(R[r * 3 + 1], b[1], R[r * 3 + 0] * b[0]));
    }
}

__device__ __forceinline__ float sel_foot(const float f[12], int idx, int c) {
    float r = f[0 + c];
    r = (idx == 1) ? f[3 + c] : r;
    r = (idx == 2) ? f[6 + c] : r;
    r = (idx == 3) ? f[9 + c] : r;
    return r;
}

// FK core on a compact 72-float pose (joint offsets 0,9,18,28,37,51,60)
__device__ __forceinline__ void fk_core(const float* Pl,
                                        const float* __restrict__ bone,
                                        float feet[12], float* fmin) {
    const float* M0 = Pl + 0;
    const float* M1 = Pl + 9;
    const float* M2 = Pl + 18;
    const float* M3 = Pl + 28;
    const float* M4 = Pl + 37;
    const float* M5 = Pl + 51;
    const float* M6 = Pl + 60;

    float R1[9], R2[9], R3[9], R4[9], R5[9], R6[9];
    mat3mul(M0, M1, R1);
    mat3mul(M0, M2, R2);
    mat3mul(R1, M3, R3);
    mat3mul(R2, M4, R4);
    mat3mul(R3, M5, R5);
    mat3mul(R4, M6, R6);

    float p0[3] = {bone[0], bone[1], bone[2]};
    float p1[3], p2[3], p3[3], p4a[3], p5[3], p6[3], p7[3], p8[3];
    mva(M0, bone + 3,  p0, p1);
    mva(M0, bone + 6,  p0, p2);
    mva(R1, bone + 9,  p1, p3);
    mva(R2, bone + 12, p2, p4a);
    mva(R3, bone + 15, p3, p5);
    mva(R4, bone + 18, p4a, p6);
    mva(R5, bone + 21, p5, p7);
    mva(R6, bone + 24, p6, p8);

    // FEET = [7,5,8,6]
    feet[0] = p7[0]; feet[1]  = p7[1]; feet[2]  = p7[2];
    feet[3] = p5[0]; feet[4]  = p5[1]; feet[5]  = p5[2];
    feet[6] = p8[0]; feet[7]  = p8[1]; feet[8]  = p8[2];
    feet[9] = p6[0]; feet[10] = p6[1]; feet[11] = p6[2];
    *fmin = fminf(fminf(p5[1], p6[1]), fminf(p7[1], p8[1]));
}

// load the 18 needed float4s of one timestep into compact Pl[72]
__device__ __forceinline__ void load_compact(const floatx4* __restrict__ pp,
                                             float Pl[72]) {
#pragma unroll
    for (int k = 0; k < 18; ++k) {
        int o = k + (k >= 7 ? 2 : 0) + (k >= 12 ? 1 : 0);   // {0..6,9..13,15..20}
        floatx4 q = pp[o];
        Pl[4 * k + 0] = q.x;
        Pl[4 * k + 1] = q.y;
        Pl[4 * k + 2] = q.z;
        Pl[4 * k + 3] = q.w;
    }
}

// inclusive wave scan (non-commutative compose, earlier = lower lane)
__device__ __forceinline__ void wave_incl_scan(float& Sx, float& Sz,
                                               float& A, float& B, int lane) {
#pragma unroll
    for (int off = 1; off < 64; off <<= 1) {
        float ox = __shfl_up(Sx, off, 64);
        float oz = __shfl_up(Sz, off, 64);
        float oA = __shfl_up(A, off, 64);
        float oB = __shfl_up(B, off, 64);
        if (lane >= off) {
            Sx += ox;
            Sz += oz;
            B = fmaxf(oB + A, B);  // B uses pre-update A
            A = oA + A;
        }
    }
}

// ---------------- single fused kernel ----------------------------------------
// Barrier-free block: waves 1-3 stream the 64-ts slice (pure copy); wave 0
// FKs from global (L2-hot), scans, then decoupled-lookback composes the
// global prefix and writes trans directly. Lookback is wave-parallel
// (64 predecessors per round) and strictly backward (deadlock-free).

__global__ __launch_bounds__(256) void k_main(const float* __restrict__ pose,
                                              const float* __restrict__ bone,
                                              const int* __restrict__ index,
                                              floatx4* __restrict__ outPose4,
                                              int* __restrict__ status,
                                              float* __restrict__ aggA,
                                              float* __restrict__ aggP,
                                              float* __restrict__ trans) {
    int tid = threadIdx.x, u = blockIdx.x;

    if (tid >= 64) {
        // ---- copy role: 18 f4 per thread, 2 batches of 9 ------------------
        int tt = tid - 64;                    // 0..191
        const floatx4* __restrict__ src = (const floatx4*)pose + (size_t)u * F4PB;
        floatx4*       __restrict__ dst = outPose4              + (size_t)u * F4PB;
#pragma unroll
        for (int bat = 0; bat < 2; ++bat) {
            floatx4 r[9];
#pragma unroll
            for (int j = 0; j < 9; ++j)
                r[j] = src[(bat * 9 + j) * 192 + tt];
#pragma unroll
            for (int j = 0; j < 9; ++j)
                __builtin_nontemporal_store(r[j], &dst[(bat * 9 + j) * 192 + tt]);
        }
        return;
    }

    // ---- wave 0: FK + velocity + inclusive scan ---------------------------
    int lane = tid;
    int t = u * BT + lane;
    int idxv = index[t];

    float Pl[72];
    load_compact((const floatx4*)(pose + (size_t)t * 216), Pl);

    float fb[12];
    if (u > 0) {
        float Pb[72], mb;
        load_compact((const floatx4*)(pose + ((size_t)u * BT - 1) * 216), Pb);
        fk_core(Pb, bone, fb, &mb);
    }

    float feet[12], fmin;
    fk_core(Pl, bone, feet, &fmin);

    float fp[12];
#pragma unroll
    for (int k = 0; k < 12; ++k) fp[k] = __shfl_up(feet[k], 1, 64);
    if (lane == 0 && u > 0) {
#pragma unroll
        for (int k = 0; k < 12; ++k) fp[k] = fb[k];
    }

    float vx, vy, vz;
    if (t == 0) {
        vx = 0.f; vy = GRAV_Y; vz = 0.f;
    } else {
        vx = sel_foot(fp, idxv, 0) - sel_foot(feet, idxv, 0);
        vy = GRAV_Y + sel_foot(fp, idxv, 1) - sel_foot(feet, idxv, 1);
        vz = sel_foot(fp, idxv, 2) - sel_foot(feet, idxv, 2);
    }
    float ix = vx, iz = vz, iA = vy, iB = FLOOR_YC - fmin;
    wave_incl_scan(ix, iz, iA, iB, lane);
    // lane 63 now holds the unit aggregate A_u

    // ---- publish aggregate (flag A) ---------------------------------------
    if (lane == 63) {
        float* a = &aggA[(size_t)u * 4];
        __hip_atomic_store(a + 0, ix, __ATOMIC_RELAXED, __HIP_MEMORY_SCOPE_AGENT);
        __hip_atomic_store(a + 1, iz, __ATOMIC_RELAXED, __HIP_MEMORY_SCOPE_AGENT);
        __hip_atomic_store(a + 2, iA, __ATOMIC_RELAXED, __HIP_MEMORY_SCOPE_AGENT);
        __hip_atomic_store(a + 3, iB, __ATOMIC_RELAXED, __HIP_MEMORY_SCOPE_AGENT);
        __threadfence();
        __hip_atomic_store(&status[u], MAGA, __ATOMIC_RELAXED, __HIP_MEMORY_SCOPE_AGENT);
    }

    // ---- wave-parallel decoupled lookback ---------------------------------
    float Rx = 0.f, Rz = 0.f, Ra = 0.f, Rb = NEG_INF;   // exclusive prefix of u
    if (u > 0) {
        int j = u - 1;
        for (;;) {
            int base = j - 63;
            int myb  = base + lane;
            int st;
            unsigned long long bP, bR;
            for (;;) {
                st = (myb >= 0)
                   ? __hip_atomic_load(&status[myb], __ATOMIC_RELAXED, __HIP_MEMORY_SCOPE_AGENT)
                   : MAGA;
                bool isP = (st == MAGP) && (myb >= 0);
                bool isR = isP || (st == MAGA);
                bP = __ballot(isP);
                bR = __ballot(isR);
                if (bP) {
                    int pl = 63 - __clzll(bP);
                    unsigned long long need = (~0ull) << pl;
                    if ((bR & need) == need) break;
                } else if (bR == ~0ull) {
                    break;
                }
                __builtin_amdgcn_s_sleep(1);
            }
            __threadfence();
            int pl = bP ? (63 - __clzll(bP)) : -1;

            float wx = 0.f, wz = 0.f, wa = 0.f, wb = NEG_INF;   // identity
            if (myb >= 0 && lane >= pl) {
                const float* s = (lane == pl) ? &aggP[(size_t)myb * 4]
                                              : &aggA[(size_t)myb * 4];
                wx = __hip_atomic_load(s + 0, __ATOMIC_RELAXED, __HIP_MEMORY_SCOPE_AGENT);
                wz = __hip_atomic_load(s + 1, __ATOMIC_RELAXED, __HIP_MEMORY_SCOPE_AGENT);
                wa = __hip_atomic_load(s + 2, __ATOMIC_RELAXED, __HIP_MEMORY_SCOPE_AGENT);
                wb = __hip_atomic_load(s + 3, __ATOMIC_RELAXED, __HIP_MEMORY_SCOPE_AGENT);
            }
            wave_incl_scan(wx, wz, wa, wb, lane);
            float Wx = __shfl(wx, 63, 64);
            float Wz = __shfl(wz, 63, 64);
            float Wa = __shfl(wa, 63, 64);
            float Wb = __shfl(wb, 63, 64);
            // R = W ∘ R  (W earlier)
            Rb = fmaxf(Wb + Ra, Rb);
            Ra = Wa + Ra;
            Rx = Wx + Rx;
            Rz = Wz + Rz;
            if (pl >= 0 || base <= 0) break;
            j -= 64;
        }
    }

    // ---- publish inclusive prefix (flag P) --------------------------------
    if (lane == 63) {
        float Px = Rx + ix;
        float Pz = Rz + iz;
        float Pb = fmaxf(Rb + iA, iB);
        float Pa = Ra + iA;
        float* p = &aggP[(size_t)u * 4];
        __hip_atomic_store(p + 0, Px, __ATOMIC_RELAXED, __HIP_MEMORY_SCOPE_AGENT);
        __hip_atomic_store(p + 1, Pz, __ATOMIC_RELAXED, __HIP_MEMORY_SCOPE_AGENT);
        __hip_atomic_store(p + 2, Pa, __ATOMIC_RELAXED, __HIP_MEMORY_SCOPE_AGENT);
        __hip_atomic_store(p + 3, Pb, __ATOMIC_RELAXED, __HIP_MEMORY_SCOPE_AGENT);
        __threadfence();
        __hip_atomic_store(&status[u], MAGP, __ATOMIC_RELAXED, __HIP_MEMORY_SCOPE_AGENT);
    }

    // ---- write trans directly from registers ------------------------------
    float entr = fmaxf(Ra, Rb);          // root_y entering this unit (r0 = 0)
    size_t t3 = (size_t)t * 3;
    trans[t3 + 0] = Rx + ix;
    trans[t3 + 1] = fmaxf(entr + iA, iB);
    trans[t3 + 2] = Rz + iz;
}

// ---------------- launch -----------------------------------------------------

extern "C" void kernel_launch(void* const* d_in, const int* in_sizes, int n_in,
                              void* d_out, int out_size, void* d_ws, size_t ws_size,
                              hipStream_t stream) {
    const float* pose  = (const float*)d_in[0];
    const float* bone  = (const float*)d_in[1];
    const int*   index = (const int*)d_in[2];
    float* out   = (float*)d_out;
    float* trans = out + POSE_FLTS;

    int*   status = (int*)d_ws;                  // NU ints (8 KB)
    float* aggA   = (float*)(status + NU);       // NU*4 floats (32 KB)
    float* aggP   = aggA + (size_t)NU * 4;       // NU*4 floats (32 KB)
    (void)ws_size; (void)n_in; (void)in_sizes; (void)out_size;

    k_main<<<NU, 256, 0, stream>>>(pose, bone, index, (floatx4*)out,
                                   status, aggA, aggP, trans);
}

// Round 14
// 254.945 us; speedup vs baseline: 1.0198x; 1.0198x over previous
//
#include <hip/hip_runtime.h>
#include <math.h>

#define T_TOTAL   131072
#define POSE_FLTS (131072 * 216)       // 28311552
#define BT        64                   // timesteps per scan unit / block
#define NU        (T_TOTAL / BT)       // 2048 units
#define F4PB      (BT * 54)            // 3456 float4 per unit slice
#define FLOOR_YC  (-0.93f)
#define GRAV_Y    (-0.0018f)
#define NEG_INF   (-INFINITY)
#define MAGA      0x5CAB1E01           // aggregate ready
#define MAGP      0x5CAB1E02           // inclusive prefix ready

typedef float floatx4 __attribute__((ext_vector_type(4)));

// ---------------- small math helpers (constant-indexed after inlining) ------

__device__ __forceinline__ void mat3mul(const float* A, const float* B, float* C) {
#pragma unroll
    for (int r = 0; r < 3; ++r) {
#pragma unroll
        for (int c = 0; c < 3; ++c) {
            C[r * 3 + c] = fmaf(A[r * 3 + 2], B[6 + c],
                           fmaf(A[r * 3 + 1], B[3 + c],
                                A[r * 3 + 0] * B[c]));
        }
    }
}

__device__ __forceinline__ void mva(const float* R, const float* b,
                                    const float* pin, float* pout) {
#pragma unroll
    for (int r = 0; r < 3; ++r) {
        pout[r] = pin[r] + fmaf(R[r * 3 + 2], b[2],
                            fmaf(R[r * 3 + 1], b[1], R[r * 3 + 0] * b[0]));
    }
}

__device__ __forceinline__ float sel_foot(const float f[12], int idx, int c) {
    float r = f[0 + c];
    r = (idx == 1) ? f[3 + c] : r;
    r = (idx == 2) ? f[6 + c] : r;
    r = (idx == 3) ? f[9 + c] : r;
    return r;
}

// FK core on a compact 72-float pose (joint offsets 0,9,18,28,37,51,60)
__device__ __forceinline__ void fk_core(const float* Pl,
                                        const float* __restrict__ bone,
                                        float feet[12], float* fmin) {
    const float* M0 = Pl + 0;
    const float* M1 = Pl + 9;
    const float* M2 = Pl + 18;
    const float* M3 = Pl + 28;
    const float* M4 = Pl + 37;
    const float* M5 = Pl + 51;
    const float* M6 = Pl + 60;

    float R1[9], R2[9], R3[9], R4[9], R5[9], R6[9];
    mat3mul(M0, M1, R1);
    mat3mul(M0, M2, R2);
    mat3mul(R1, M3, R3);
    mat3mul(R2, M4, R4);
    mat3mul(R3, M5, R5);
    mat3mul(R4, M6, R6);

    float p0[3] = {bone[0], bone[1], bone[2]};
    float p1[3], p2[3], p3[3], p4a[3], p5[3], p6[3], p7[3], p8[3];
    mva(M0, bone + 3,  p0, p1);
    mva(M0, bone + 6,  p0, p2);
    mva(R1, bone + 9,  p1, p3);
    mva(R2, bone + 12, p2, p4a);
    mva(R3, bone + 15, p3, p5);
    mva(R4, bone + 18, p4a, p6);
    mva(R5, bone + 21, p5, p7);
    mva(R6, bone + 24, p6, p8);

    // FEET = [7,5,8,6]
    feet[0] = p7[0]; feet[1]  = p7[1]; feet[2]  = p7[2];
    feet[3] = p5[0]; feet[4]  = p5[1]; feet[5]  = p5[2];
    feet[6] = p8[0]; feet[7]  = p8[1]; feet[8]  = p8[2];
    feet[9] = p6[0]; feet[10] = p6[1]; feet[11] = p6[2];
    *fmin = fminf(fminf(p5[1], p6[1]), fminf(p7[1], p8[1]));
}

// load the 18 needed float4s of one timestep into compact Pl[72]
__device__ __forceinline__ void load_compact(const floatx4* __restrict__ pp,
                                             float Pl[72]) {
#pragma unroll
    for (int k = 0; k < 18; ++k) {
        int o = k + (k >= 7 ? 2 : 0) + (k >= 12 ? 1 : 0);   // {0..6,9..13,15..20}
        floatx4 q = pp[o];
        Pl[4 * k + 0] = q.x;
        Pl[4 * k + 1] = q.y;
        Pl[4 * k + 2] = q.z;
        Pl[4 * k + 3] = q.w;
    }
}

// inclusive wave scan (non-commutative compose, earlier = lower lane)
__device__ __forceinline__ void wave_incl_scan(float& Sx, float& Sz,
                                               float& A, float& B, int lane) {
#pragma unroll
    for (int off = 1; off < 64; off <<= 1) {
        float ox = __shfl_up(Sx, off, 64);
        float oz = __shfl_up(Sz, off, 64);
        float oA = __shfl_up(A, off, 64);
        float oB = __shfl_up(B, off, 64);
        if (lane >= off) {
            Sx += ox;
            Sz += oz;
            B = fmaxf(oB + A, B);  // B uses pre-update A
            A = oA + A;
        }
    }
}

// ---------------- single fused kernel ----------------------------------------
// Barrier-free block: waves 1-3 stream the 64-ts slice (pure copy); wave 0
// FKs from global (L2-hot), scans, then decoupled-lookback composes the
// global prefix and writes trans directly. Lookback is wave-parallel
// (64 predecessors per round) and strictly backward (deadlock-free).

__global__ __launch_bounds__(256) void k_main(const float* __restrict__ pose,
                                              const float* __restrict__ bone,
                                              const int* __restrict__ index,
                                              floatx4* __restrict__ outPose4,
                                              int* __restrict__ status,
                                              float* __restrict__ aggA,
                                              float* __restrict__ aggP,
                                              float* __restrict__ trans) {
    int tid = threadIdx.x, u = blockIdx.x;

    if (tid >= 64) {
        // ---- copy role: 18 f4 per thread, 2 batches of 9 ------------------
        int tt = tid - 64;                    // 0..191
        const floatx4* __restrict__ src = (const floatx4*)pose + (size_t)u * F4PB;
        floatx4*       __restrict__ dst = outPose4              + (size_t)u * F4PB;
#pragma unroll
        for (int bat = 0; bat < 2; ++bat) {
            floatx4 r[9];
#pragma unroll
            for (int j = 0; j < 9; ++j)
                r[j] = src[(bat * 9 + j) * 192 + tt];
#pragma unroll
            for (int j = 0; j < 9; ++j)
                __builtin_nontemporal_store(r[j], &dst[(bat * 9 + j) * 192 + tt]);
        }
        return;
    }

    // ---- wave 0: FK + velocity + inclusive scan ---------------------------
    int lane = tid;
    int t = u * BT + lane;
    int idxv = index[t];

    float Pl[72];
    load_compact((const floatx4*)(pose + (size_t)t * 216), Pl);

    float fb[12];
    if (u > 0) {
        float Pb[72], mb;
        load_compact((const floatx4*)(pose + ((size_t)u * BT - 1) * 216), Pb);
        fk_core(Pb, bone, fb, &mb);
    }

    float feet[12], fmin;
    fk_core(Pl, bone, feet, &fmin);

    float fp[12];
#pragma unroll
    for (int k = 0; k < 12; ++k) fp[k] = __shfl_up(feet[k], 1, 64);
    if (lane == 0 && u > 0) {
#pragma unroll
        for (int k = 0; k < 12; ++k) fp[k] = fb[k];
    }

    float vx, vy, vz;
    if (t == 0) {
        vx = 0.f; vy = GRAV_Y; vz = 0.f;
    } else {
        vx = sel_foot(fp, idxv, 0) - sel_foot(feet, idxv, 0);
        vy = GRAV_Y + sel_foot(fp, idxv, 1) - sel_foot(feet, idxv, 1);
        vz = sel_foot(fp, idxv, 2) - sel_foot(feet, idxv, 2);
    }
    float ix = vx, iz = vz, iA = vy, iB = FLOOR_YC - fmin;
    wave_incl_scan(ix, iz, iA, iB, lane);
    // lane 63 now holds the unit aggregate A_u

    // ---- publish aggregate (flag A) ---------------------------------------
    if (lane == 63) {
        float* a = &aggA[(size_t)u * 4];
        __hip_atomic_store(a + 0, ix, __ATOMIC_RELAXED, __HIP_MEMORY_SCOPE_AGENT);
        __hip_atomic_store(a + 1, iz, __ATOMIC_RELAXED, __HIP_MEMORY_SCOPE_AGENT);
        __hip_atomic_store(a + 2, iA, __ATOMIC_RELAXED, __HIP_MEMORY_SCOPE_AGENT);
        __hip_atomic_store(a + 3, iB, __ATOMIC_RELAXED, __HIP_MEMORY_SCOPE_AGENT);
        __threadfence();
        __hip_atomic_store(&status[u], MAGA, __ATOMIC_RELAXED, __HIP_MEMORY_SCOPE_AGENT);
    }

    // ---- wave-parallel decoupled lookback ---------------------------------
    float Rx = 0.f, Rz = 0.f, Ra = 0.f, Rb = NEG_INF;   // exclusive prefix of u
    if (u > 0) {
        int j = u - 1;
        for (;;) {
            int base = j - 63;
            int myb  = base + lane;
            int st;
            unsigned long long bP, bR;
            for (;;) {
                st = (myb >= 0)
                   ? __hip_atomic_load(&status[myb], __ATOMIC_RELAXED, __HIP_MEMORY_SCOPE_AGENT)
                   : MAGA;
                bool isP = (st == MAGP) && (myb >= 0);
                bool isR = isP || (st == MAGA);
                bP = __ballot(isP);
                bR = __ballot(isR);
                if (bP) {
                    int pl = 63 - __clzll(bP);
                    unsigned long long need = (~0ull) << pl;
                    if ((bR & need) == need) break;
                } else if (bR == ~0ull) {
                    break;
                }
                __builtin_amdgcn_s_sleep(1);
            }
            __threadfence();
            int pl = bP ? (63 - __clzll(bP)) : -1;

            float wx = 0.f, wz = 0.f, wa = 0.f, wb = NEG_INF;   // identity
            if (myb >= 0 && lane >= pl) {
                const float* s = (lane == pl) ? &aggP[(size_t)myb * 4]
                                              : &aggA[(size_t)myb * 4];
                wx = __hip_atomic_load(s + 0, __ATOMIC_RELAXED, __HIP_MEMORY_SCOPE_AGENT);
                wz = __hip_atomic_load(s + 1, __ATOMIC_RELAXED, __HIP_MEMORY_SCOPE_AGENT);
                wa = __hip_atomic_load(s + 2, __ATOMIC_RELAXED, __HIP_MEMORY_SCOPE_AGENT);
                wb = __hip_atomic_load(s + 3, __ATOMIC_RELAXED, __HIP_MEMORY_SCOPE_AGENT);
            }
            wave_incl_scan(wx, wz, wa, wb, lane);
            float Wx = __shfl(wx, 63, 64);
            float Wz = __shfl(wz, 63, 64);
            float Wa = __shfl(wa, 63, 64);
            float Wb = __shfl(wb, 63, 64);
            // R = W ∘ R  (W earlier)
            Rb = fmaxf(Wb + Ra, Rb);
            Ra = Wa + Ra;
            Rx = Wx + Rx;
            Rz = Wz + Rz;
            if (pl >= 0 || base <= 0) break;
            j -= 64;
        }
    }

    // ---- publish inclusive prefix (flag P) --------------------------------
    if (lane == 63) {
        float Px = Rx + ix;
        float Pz = Rz + iz;
        float Pb = fmaxf(Rb + iA, iB);
        float Pa = Ra + iA;
        float* p = &aggP[(size_t)u * 4];
        __hip_atomic_store(p + 0, Px, __ATOMIC_RELAXED, __HIP_MEMORY_SCOPE_AGENT);
        __hip_atomic_store(p + 1, Pz, __ATOMIC_RELAXED, __HIP_MEMORY_SCOPE_AGENT);
        __hip_atomic_store(p + 2, Pa, __ATOMIC_RELAXED, __HIP_MEMORY_SCOPE_AGENT);
        __hip_atomic_store(p + 3, Pb, __ATOMIC_RELAXED, __HIP_MEMORY_SCOPE_AGENT);
        __threadfence();
        __hip_atomic_store(&status[u], MAGP, __ATOMIC_RELAXED, __HIP_MEMORY_SCOPE_AGENT);
    }

    // ---- write trans directly from registers ------------------------------
    float entr = fmaxf(Ra, Rb);          // root_y entering this unit (r0 = 0)
    size_t t3 = (size_t)t * 3;
    trans[t3 + 0] = Rx + ix;
    trans[t3 + 1] = fmaxf(entr + iA, iB);
    trans[t3 + 2] = Rz + iz;
}

// ---------------- launch -----------------------------------------------------

extern "C" void kernel_launch(void* const* d_in, const int* in_sizes, int n_in,
                              void* d_out, int out_size, void* d_ws, size_t ws_size,
                              hipStream_t stream) {
    const float* pose  = (const float*)d_in[0];
    const float* bone  = (const float*)d_in[1];
    const int*   index = (const int*)d_in[2];
    float* out   = (float*)d_out;
    float* trans = out + POSE_FLTS;

    int*   status = (int*)d_ws;                  // NU ints (8 KB)
    float* aggA   = (float*)(status + NU);       // NU*4 floats (32 KB)
    float* aggP   = aggA + (size_t)NU * 4;       // NU*4 floats (32 KB)
    (void)ws_size; (void)n_in; (void)in_sizes; (void)out_size;

    k_main<<<NU, 256, 0, stream>>>(pose, bone, index, (floatx4*)out,
                                   status, aggA, aggP, trans);
}

// Round 15
// 46.253 us; speedup vs baseline: 5.6210x; 5.5120x over previous
//
#include <hip/hip_runtime.h>
#include <math.h>

#define T_TOTAL   131072
#define POSE_FLTS (131072 * 216)       // 28311552
#define BT        64                   // timesteps per scan unit / block
#define NU        (T_TOTAL / BT)       // 2048 units
#define F4PB      (BT * 54)            // 3456 float4 per unit slice
#define FLOOR_YC  (-0.93f)
#define GRAV_Y    (-0.0018f)
#define NEG_INF   (-INFINITY)

typedef float floatx4 __attribute__((ext_vector_type(4)));

// ---------------- small math helpers (constant-indexed after inlining) ------

__device__ __forceinline__ void mat3mul(const float* A, const float* B, float* C) {
#pragma unroll
    for (int r = 0; r < 3; ++r) {
#pragma unroll
        for (int c = 0; c < 3; ++c) {
            C[r * 3 + c] = fmaf(A[r * 3 + 2], B[6 + c],
                           fmaf(A[r * 3 + 1], B[3 + c],
                                A[r * 3 + 0] * B[c]));
        }
    }
}

__device__ __forceinline__ void mva(const float* R, const float* b,
                                    const float* pin, float* pout) {
#pragma unroll
    for (int r = 0; r < 3; ++r) {
        pout[r] = pin[r] + fmaf(R[r * 3 + 2], b[2],
                            fmaf(R[r * 3 + 1], b[1], R[r * 3 + 0] * b[0]));
    }
}

__device__ __forceinline__ float sel_foot(const float f[12], int idx, int c) {
    float r = f[0 + c];
    r = (idx == 1) ? f[3 + c] : r;
    r = (idx == 2) ? f[6 + c] : r;
    r = (idx == 3) ? f[9 + c] : r;
    return r;
}

// FK core on a compact 72-float pose (joint offsets 0,9,18,28,37,51,60)
__device__ __forceinline__ void fk_core(const float* Pl,
                                        const float* __restrict__ bone,
                                        float feet[12], float* fmin) {
    const float* M0 = Pl + 0;
    const float* M1 = Pl + 9;
    const float* M2 = Pl + 18;
    const float* M3 = Pl + 28;
    const float* M4 = Pl + 37;
    const float* M5 = Pl + 51;
    const float* M6 = Pl + 60;

    float R1[9], R2[9], R3[9], R4[9], R5[9], R6[9];
    mat3mul(M0, M1, R1);
    mat3mul(M0, M2, R2);
    mat3mul(R1, M3, R3);
    mat3mul(R2, M4, R4);
    mat3mul(R3, M5, R5);
    mat3mul(R4, M6, R6);

    float p0[3] = {bone[0], bone[1], bone[2]};
    float p1[3], p2[3], p3[3], p4a[3], p5[3], p6[3], p7[3], p8[3];
    mva(M0, bone + 3,  p0, p1);
    mva(M0, bone + 6,  p0, p2);
    mva(R1, bone + 9,  p1, p3);
    mva(R2, bone + 12, p2, p4a);
    mva(R3, bone + 15, p3, p5);
    mva(R4, bone + 18, p4a, p6);
    mva(R5, bone + 21, p5, p7);
    mva(R6, bone + 24, p6, p8);

    // FEET = [7,5,8,6]
    feet[0] = p7[0]; feet[1]  = p7[1]; feet[2]  = p7[2];
    feet[3] = p5[0]; feet[4]  = p5[1]; feet[5]  = p5[2];
    feet[6] = p8[0]; feet[7]  = p8[1]; feet[8]  = p8[2];
    feet[9] = p6[0]; feet[10] = p6[1]; feet[11] = p6[2];
    *fmin = fminf(fminf(p5[1], p6[1]), fminf(p7[1], p8[1]));
}

// load the 18 needed float4s of one timestep into compact Pl[72]
__device__ __forceinline__ void load_compact(const floatx4* __restrict__ pp,
                                             float Pl[72]) {
#pragma unroll
    for (int k = 0; k < 18; ++k) {
        int o = k + (k >= 7 ? 2 : 0) + (k >= 12 ? 1 : 0);   // {0..6,9..13,15..20}
        floatx4 q = pp[o];
        Pl[4 * k + 0] = q.x;
        Pl[4 * k + 1] = q.y;
        Pl[4 * k + 2] = q.z;
        Pl[4 * k + 3] = q.w;
    }
}

// inclusive wave scan (non-commutative compose, earlier = lower lane)
__device__ __forceinline__ void wave_incl_scan(float& Sx, float& Sz,
                                               float& A, float& B, int lane) {
#pragma unroll
    for (int off = 1; off < 64; off <<= 1) {
        float ox = __shfl_up(Sx, off, 64);
        float oz = __shfl_up(Sz, off, 64);
        float oA = __shfl_up(A, off, 64);
        float oB = __shfl_up(B, off, 64);
        if (lane >= off) {
            Sx += ox;
            Sz += oz;
            B = fmaxf(oB + A, B);  // B uses pre-update A
            A = oA + A;
        }
    }
}

// ---------------- main kernel ------------------------------------------------
// Barrier-free: waves 1-3 stream the 64-ts slice (pure copy, no LDS); wave 0
// reads its own FK data from global (L2-hot from the same block's copy),
// FKs the boundary ts on all lanes (uniform loads), scans, writes vws/agg.

__global__ __launch_bounds__(256) void k_main(const float* __restrict__ pose,
                                              const float* __restrict__ bone,
                                              const int* __restrict__ index,
                                              floatx4* __restrict__ outPose4,
                                              float4* __restrict__ vws,
                                              float4* __restrict__ wsAgg) {
    int tid = threadIdx.x, u = blockIdx.x;

    if (tid >= 64) {
        // ---- copy role: 18 f4 per thread, 2 batches of 9 ------------------
        int tt = tid - 64;                    // 0..191
        const floatx4* __restrict__ src = (const floatx4*)pose + (size_t)u * F4PB;
        floatx4*       __restrict__ dst = outPose4              + (size_t)u * F4PB;
#pragma unroll
        for (int bat = 0; bat < 2; ++bat) {
            floatx4 r[9];
#pragma unroll
            for (int j = 0; j < 9; ++j)
                r[j] = src[(bat * 9 + j) * 192 + tt];
#pragma unroll
            for (int j = 0; j < 9; ++j)
                __builtin_nontemporal_store(r[j], &dst[(bat * 9 + j) * 192 + tt]);
        }
        return;
    }

    // ---- wave 0: FK + velocity + inclusive scan ---------------------------
    int lane = tid;
    int t = u * BT + lane;
    int idxv = index[t];

    // issue own-ts loads first (latency hides under boundary FK)
    float Pl[72];
    load_compact((const floatx4*)(pose + (size_t)t * 216), Pl);

    // boundary ts (u*BT-1): lane-uniform loads, FK on all lanes (no divergence)
    float fb[12];
    if (u > 0) {
        float Pb[72], mb;
        load_compact((const floatx4*)(pose + ((size_t)u * BT - 1) * 216), Pb);
        fk_core(Pb, bone, fb, &mb);
    }

    float feet[12], fmin;
    fk_core(Pl, bone, feet, &fmin);

    float fp[12];
#pragma unroll
    for (int k = 0; k < 12; ++k) fp[k] = __shfl_up(feet[k], 1, 64);
    if (lane == 0 && u > 0) {
#pragma unroll
        for (int k = 0; k < 12; ++k) fp[k] = fb[k];
    }

    float vx, vy, vz;
    if (t == 0) {
        vx = 0.f; vy = GRAV_Y; vz = 0.f;
    } else {
        vx = sel_foot(fp, idxv, 0) - sel_foot(feet, idxv, 0);
        vy = GRAV_Y + sel_foot(fp, idxv, 1) - sel_foot(feet, idxv, 1);
        vz = sel_foot(fp, idxv, 2) - sel_foot(feet, idxv, 2);
    }
    float ix = vx, iz = vz, iA = vy, iB = FLOOR_YC - fmin;
    wave_incl_scan(ix, iz, iA, iB, lane);

    vws[(size_t)t] = make_float4(ix, iz, iA, iB);       // inclusive state
    if (lane == 63) wsAgg[u] = make_float4(ix, iz, iA, iB);
}

// ---------------- apply kernel (folds phase2 + phase3) -----------------------
// Every block redundantly scans the 2048 unit aggregates (32 KB from L2),
// extracts the entering state for its 4 units, and applies to 256 elements.

__global__ __launch_bounds__(256) void k_apply(const float4* __restrict__ wsAgg,
                                               const float4* __restrict__ vws,
                                               float* __restrict__ trans) {
    __shared__ float4 wtot[4];
    __shared__ float4 pre[4];
    int tid = threadIdx.x, bk = blockIdx.x;
    int lane = tid & 63, wv = tid >> 6;

    // thread composes aggregates [tid*8, tid*8+8)
    float4 a[8];
#pragma unroll
    for (int k = 0; k < 8; ++k) a[k] = wsAgg[tid * 8 + k];
    float cx = a[0].x, cz = a[0].y, ca = a[0].z, cb = a[0].w;
#pragma unroll
    for (int k = 1; k < 8; ++k) {
        cb = fmaxf(cb + a[k].z, a[k].w);
        ca += a[k].z;
        cx += a[k].x; cz += a[k].y;
    }

    float sx = cx, sz = cz, sa = ca, sb = cb;
    wave_incl_scan(sx, sz, sa, sb, lane);
    if (lane == 63) wtot[wv] = make_float4(sx, sz, sa, sb);

    // lane-exclusive from inclusive
    float ex = __shfl_up(sx, 1, 64);
    float ez = __shfl_up(sz, 1, 64);
    float eA = __shfl_up(sa, 1, 64);
    float eB = __shfl_up(sb, 1, 64);
    if (lane == 0) { ex = 0.f; ez = 0.f; eA = 0.f; eB = NEG_INF; }
    __syncthreads();

    // wave prefix (earlier waves, composed in order)
    float wx = 0.f, wz = 0.f, wA = 0.f, wB = NEG_INF;
    for (int w = 0; w < wv; ++w) {
        float4 c = wtot[w];
        wx += c.x; wz += c.y;
        wB = fmaxf(wB + c.z, c.w);
        wA += c.z;
    }
    float tx = wx + ex, tz = wz + ez;
    float tB = fmaxf(wB + eA, eB);
    float tA = wA + eA;

    // block bk needs entering states for units bk*4 .. bk*4+3; those agg
    // indices live in thread (bk>>1)'s chunk of 8.
    if (tid == (bk >> 1)) {
        int j0 = bk * 4 - tid * 8;       // 0 or 4
        float px = tx, pz = tz, pA = tA, pB = tB;
#pragma unroll
        for (int k = 0; k < 8; ++k) {
            if (k >= j0 && k < j0 + 4)
                pre[k - j0] = make_float4(px, pz, fmaxf(pA, pB), 0.f);
            pB = fmaxf(pB + a[k].z, a[k].w);
            pA += a[k].z;
            px += a[k].x; pz += a[k].y;
        }
    }
    __syncthreads();

    float4 bin = pre[wv];
    size_t t = ((size_t)bk * 4 + wv) * 64 + lane;
    float4 v = vws[t];
    trans[t * 3 + 0] = bin.x + v.x;
    trans[t * 3 + 1] = fmaxf(bin.z + v.z, v.w);
    trans[t * 3 + 2] = bin.y + v.y;
}

// ---------------- launch -----------------------------------------------------

extern "C" void kernel_launch(void* const* d_in, const int* in_sizes, int n_in,
                              void* d_out, int out_size, void* d_ws, size_t ws_size,
                              hipStream_t stream) {
    const float* pose  = (const float*)d_in[0];
    const float* bone  = (const float*)d_in[1];
    const int*   index = (const int*)d_in[2];
    float* out   = (float*)d_out;
    float* trans = out + POSE_FLTS;

    float4* vws   = (float4*)d_ws;         // T entries (2 MB)
    float4* wsAgg = vws + T_TOTAL;         // NU entries
    (void)ws_size; (void)n_in; (void)in_sizes; (void)out_size;

    k_main <<<NU, 256, 0, stream>>>(pose, bone, index, (floatx4*)out, vws, wsAgg);
    k_apply<<<NU / 4, 256, 0, stream>>>(wsAgg, vws, trans);
}